// Round 6
// baseline (338.293 us; speedup 1.0000x reference)
//
#include <hip/hip_runtime.h>
#include <hip/hip_fp8.h>
#include <cstdint>
#include <cmath>

// Problem constants
#define B_   4
#define C_   512
#define HW_  4096
#define G_   32
#define CPG_ 16
#define EPS_ 1e-6f
#define SCALE_ 0.04419417382415922f  // 1/sqrt(512)
#define PSCALE_ 0.0625f              // P pre-scale; cancels in acc/rowsum ratio
#define SEXPC_ 0.063758715306f       // SCALE * log2(e): exp(a*S)*2^-4 = 2^(a*SEXPC - 4)

// ---------------------------------------------------------------------------
// Column permutation (sigma): GEMM epilogues store outputs in the MFMA
// C-layout packed order. Within each 64-col group, stored position
// p = fr*4 + j holds true column c = j*16 + fr. Invariant under contraction
// as long as producer & consumer agree.
//
// Weight scaling: fp8 weights are stored x16; the MFMA e8m0 scale operand
// 0x7B (= 2^-4) folds the 1/16 back in HW. Same trick for hmT8.
//
// R14 (post-mortem R13): 8-phase 256^2 port REGRESSED (62us, MfmaUtil 20.7)
// — finer phases double the barrier rate per MFMA-cycle for the fat 34.5-cyc
// MX MFMA (8 MFMA/2bar vs 2-phase's 16/2bar). All evidence now points at
// INTRA-WAVE serialization: ds_read -> lgkm -> MFMA is a serial chain per
// K-step. Fix: register fragment double-buffer with the MFMA shifted one
// tile behind the ds_reads:
//   step t: vmcnt(0) [T(t+1) resident, issued a full step ago]
//           barrier  [T(t+1) visible; all waves' T(t) reg-reads lgkm-drained]
//           stage T(t+2) -> buf[t&1]   [safe: T(t) consumed from REGISTERS]
//           ds_read T(t+1) -> regs_nxt  ||  MFMA T(t) from regs_cur (552 cyc)
//           lgkm(0); swap reg sets
// One barrier per K-step; the 16 ds_reads hide under the MFMA cluster.
// Ping-pong reg sets are NAMED (2x unrolled loop) to avoid dynamic indexing.
// ---------------------------------------------------------------------------

typedef __bf16 bf16_t;
typedef __bf16 bf16x8 __attribute__((ext_vector_type(8)));
typedef float  f32x4  __attribute__((ext_vector_type(4)));
typedef int    i32x4  __attribute__((ext_vector_type(4)));
typedef int    i32x8  __attribute__((ext_vector_type(8)));
typedef unsigned int u32;
typedef __hip_fp8_e4m3 fp8_t;  // OCP e4m3fn on gfx950

// Async global->LDS copy, 16B per lane. LDS dest is wave-uniform base + lane*16.
__device__ __forceinline__ void cp16(const void* g, void* l) {
  __builtin_amdgcn_global_load_lds((__attribute__((address_space(1))) u32*)(g),
                                   (__attribute__((address_space(3))) u32*)(l),
                                   16, 0, 0);
}

// Raw v_exp_f32 (2^x). s_nop 1 covers the trans->consumer wait-state
// conservatively (inline asm is opaque to the hazard recognizer).
__device__ __forceinline__ float fexp2(float x) {
  float r;
  asm("v_exp_f32 %0, %1\n\ts_nop 1" : "=v"(r) : "v"(x));
  return r;
}

__device__ __forceinline__ void zero_acc(f32x4 acc[4][4]) {
  f32x4 z = {0.f, 0.f, 0.f, 0.f};
#pragma unroll
  for (int i = 0; i < 4; ++i)
#pragma unroll
    for (int j = 0; j < 4; ++j) acc[i][j] = z;
}

// MX-fp8 BT GEMM mainloop (BK=128): mfma_scale_f32_16x16x128_f8f6f4, fmt 0
// (e4m3), per-operand e8m0 scales SA/SB (0x7F = 1.0, 0x7B = 2^-4).
// LDS rows are 128 B (8 chunks); chunk-rotation swizzle mod 8 keeps staging
// and the paired ds_read_b128 fragment reads at the LDS bank floor.
// Register-dbuf pipeline (see header comment): one barrier per K-step,
// MFMA consumes the PREVIOUS tile's fragments from registers while this
// step's ds_reads land.

// One pipeline step. ac/bc: fragment set being consumed by MFMA (tile tt).
// an/bn: set being filled by ds_read (tile tt+1) from rdA/rdB.
// stA/stB: LDS buffer receiving tile tt+2 (the buffer tile tt lived in).
#define GEMM_STEP(tt, ac, bc, an, bn, rdA, rdB, stA, stB)                      \
  {                                                                            \
    asm volatile("s_waitcnt vmcnt(0)" ::: "memory");                           \
    __builtin_amdgcn_s_barrier();                                              \
    if ((tt) + 2 < nT) {                                                       \
      _Pragma("unroll")                                                        \
      for (int cc = 0; cc < 4; ++cc) {                                         \
        cp16(gA + (size_t)(cc * 8) * lda, (stA) + lofs + cc * 1024);           \
        cp16(gB + (size_t)(cc * 8) * ldb, (stB) + lofs + cc * 1024);           \
      }                                                                        \
      gA += 128; gB += 128;                                                    \
    }                                                                          \
    if ((tt) + 1 < nT) {                                                       \
      _Pragma("unroll")                                                        \
      for (int i = 0; i < 4; ++i) {                                            \
        const int ro = (wm + i * 16 + fr) * 128;                               \
        i32x4 lo = *(const i32x4*)((rdA) + ro + co0);                          \
        i32x4 hi = *(const i32x4*)((rdA) + ro + co1);                          \
        an[i] = __builtin_shufflevector(lo, hi, 0, 1, 2, 3, 4, 5, 6, 7);       \
      }                                                                        \
      _Pragma("unroll")                                                        \
      for (int j = 0; j < 4; ++j) {                                            \
        const int ro = (wn + j * 16 + fr) * 128;                               \
        i32x4 lo = *(const i32x4*)((rdB) + ro + co0);                          \
        i32x4 hi = *(const i32x4*)((rdB) + ro + co1);                          \
        bn[j] = __builtin_shufflevector(lo, hi, 0, 1, 2, 3, 4, 5, 6, 7);       \
      }                                                                        \
    }                                                                          \
    __builtin_amdgcn_s_setprio(1);                                             \
    _Pragma("unroll")                                                          \
    for (int i = 0; i < 4; ++i) {                                              \
      _Pragma("unroll")                                                        \
      for (int j = 0; j < 4; ++j)                                              \
        acc[i][j] = __builtin_amdgcn_mfma_scale_f32_16x16x128_f8f6f4(          \
            ac[i], bc[j], acc[i][j], 0, 0, 0, SA, 0, SB);                      \
      if (ROWSUM)                                                              \
        accl[i] = __builtin_amdgcn_mfma_scale_f32_16x16x128_f8f6f4(            \
            ac[i], vones, accl[i], 0, 0, 0, SA, 0, 0x7F);                      \
    }                                                                          \
    __builtin_amdgcn_s_setprio(0);                                             \
    asm volatile("s_waitcnt lgkmcnt(0)" ::: "memory");                         \
  }

template <bool ROWSUM, int SA = 0x7F, int SB = 0x7F>
__device__ __forceinline__ void gemm_bt_mx(const unsigned char* __restrict__ A,
                                           const unsigned char* __restrict__ B,
                                           int K, int lda, int ldb,
                                           f32x4 acc[4][4], f32x4 accl[4],
                                           unsigned char* AsB, unsigned char* BsB) {
  const int tid  = threadIdx.x;
  const int wave = tid >> 6;
  const int lane = tid & 63;
  const int wm = (wave >> 1) * 64;
  const int wn = (wave & 1) * 64;
  // staging: per cp16 call lane covers row (lane>>3), LDS chunk (lane&7);
  // rotation: LDS chunk c of row r holds global chunk (c - r) & 7.
  const int srow = lane >> 3;
  const int gch  = ((lane & 7) - srow) & 7;
  const unsigned char* gA = A + (size_t)(wave * 32 + srow) * lda + gch * 16;
  const unsigned char* gB = B + (size_t)(wave * 32 + srow) * ldb + gch * 16;
  const int lofs = wave * 32 * 128;
  const int fr = lane & 15;
  const int q  = lane >> 4;
  // lane wants global chunks 2q, 2q+1 of its row (32 B = K-128 fragment)
  const int co0 = ((2 * q     + fr) & 7) * 16;
  const int co1 = ((2 * q + 1 + fr) & 7) * 16;
  const i32x8 vones = {0x38383838, 0x38383838, 0x38383838, 0x38383838,
                       0x38383838, 0x38383838, 0x38383838, 0x38383838};

  const int nT = K >> 7;   // always >= 4 and even in this pipeline
  // prologue: stage T0 -> buf0, T1 -> buf1
#pragma unroll
  for (int cc = 0; cc < 4; ++cc) {
    cp16(gA + (size_t)(cc * 8) * lda, AsB + lofs + cc * 1024);
    cp16(gB + (size_t)(cc * 8) * ldb, BsB + lofs + cc * 1024);
  }
  gA += 128; gB += 128;
#pragma unroll
  for (int cc = 0; cc < 4; ++cc) {
    cp16(gA + (size_t)(cc * 8) * lda, AsB + 16384 + lofs + cc * 1024);
    cp16(gB + (size_t)(cc * 8) * ldb, BsB + 16384 + lofs + cc * 1024);
  }
  gA += 128; gB += 128;
  asm volatile("s_waitcnt vmcnt(8)" ::: "memory");   // T0 resident (T1 flying)
  __builtin_amdgcn_s_barrier();

  i32x8 a0[4], b0[4], a1[4], b1[4];
  // read T0 fragments -> set0
#pragma unroll
  for (int i = 0; i < 4; ++i) {
    const int ro = (wm + i * 16 + fr) * 128;
    i32x4 lo = *(const i32x4*)(AsB + ro + co0);
    i32x4 hi = *(const i32x4*)(AsB + ro + co1);
    a0[i] = __builtin_shufflevector(lo, hi, 0, 1, 2, 3, 4, 5, 6, 7);
  }
#pragma unroll
  for (int j = 0; j < 4; ++j) {
    const int ro = (wn + j * 16 + fr) * 128;
    i32x4 lo = *(const i32x4*)(BsB + ro + co0);
    i32x4 hi = *(const i32x4*)(BsB + ro + co1);
    b0[j] = __builtin_shufflevector(lo, hi, 0, 1, 2, 3, 4, 5, 6, 7);
  }
  asm volatile("s_waitcnt lgkmcnt(0)" ::: "memory");

  // steady loop, 2 steps per iteration (named reg-set ping-pong).
  // even t: MFMA set0 (tile t); read tile t+1 from buf1 -> set1; stage t+2 -> buf0
  // odd  t: MFMA set1;          read tile t+1 from buf0 -> set0; stage t+2 -> buf1
#pragma unroll 1
  for (int t = 0; t < nT; t += 2) {
    GEMM_STEP(t,     a0, b0, a1, b1, AsB + 16384, BsB + 16384, AsB,         BsB);
    GEMM_STEP(t + 1, a1, b1, a0, b0, AsB,         BsB,         AsB + 16384, BsB + 16384);
  }
}

// ---------------- prep: GroupNorm partials + weight casts (merged) ----------

// blocks [0,1024): partial GN stats (8 hw-chunks per group, 2 atomics each).
// blocks [1024,2048): wqkv8 = fp8(qkv_w*16) plain; wproj8 = fp8(proj_w*16)
// with sigma-permuted c columns.
__global__ void __launch_bounds__(256) prep_kernel(const float* __restrict__ x,
                                                   float* __restrict__ stats,
                                                   const float* __restrict__ qkv_w,
                                                   const float* __restrict__ proj_w,
                                                   fp8_t* __restrict__ wqkv8,
                                                   fp8_t* __restrict__ wproj8) {
  __shared__ float rs[256], rss[256];
  const int n = blockIdx.x;
  if (n < 1024) {
    const int bg = n >> 3;       // group id 0..127
    const int ch = n & 7;        // hw chunk 0..7
    const float4* base = (const float4*)(x + (size_t)bg * (CPG_ * HW_)) +
                         (size_t)ch * (CPG_ * HW_ / 4 / 8);
    float s = 0.f, ss = 0.f;
    for (int i = threadIdx.x; i < CPG_ * HW_ / 4 / 8; i += 256) {
      float4 v = base[i];
      s  += v.x + v.y + v.z + v.w;
      ss += v.x * v.x + v.y * v.y + v.z * v.z + v.w * v.w;
    }
    rs[threadIdx.x] = s; rss[threadIdx.x] = ss;
    __syncthreads();
    for (int st = 128; st > 0; st >>= 1) {
      if ((int)threadIdx.x < st) {
        rs[threadIdx.x]  += rs[threadIdx.x + st];
        rss[threadIdx.x] += rss[threadIdx.x + st];
      }
      __syncthreads();
    }
    if (threadIdx.x == 0) {
      atomicAdd(&stats[bg * 2 + 0], rs[0]);
      atomicAdd(&stats[bg * 2 + 1], rss[0]);
    }
  } else {
    const int idx = (n - 1024) * 256 + threadIdx.x;   // quad index
    const int t = idx * 4;
    const int nq = 1536 * 512;
    if (t < nq) {
      u32 dw = 0;
      dw = (u32)__builtin_amdgcn_cvt_pk_fp8_f32(qkv_w[t] * 16.f, qkv_w[t + 1] * 16.f, (int)dw, false);
      dw = (u32)__builtin_amdgcn_cvt_pk_fp8_f32(qkv_w[t + 2] * 16.f, qkv_w[t + 3] * 16.f, (int)dw, true);
      *(u32*)((unsigned char*)wqkv8 + t) = dw;
    } else {
      const int tt = t - nq;          // o*512 + p, p multiple of 4
      const int o = tt >> 9;
      const int p = tt & 511;
      float v[4];
#pragma unroll
      for (int e = 0; e < 4; ++e) {
        const int pe = p + e;
        const int off = pe & 63;
        const int c = (pe & ~63) + ((off & 3) << 4) + (off >> 2);  // sigma(pe)
        v[e] = proj_w[(o << 9) + c] * 16.f;
      }
      u32 dw = 0;
      dw = (u32)__builtin_amdgcn_cvt_pk_fp8_f32(v[0], v[1], (int)dw, false);
      dw = (u32)__builtin_amdgcn_cvt_pk_fp8_f32(v[2], v[3], (int)dw, true);
      *(u32*)((unsigned char*)wproj8 + tt) = dw;
    }
  }
}

// normalize + transpose: x[b][c][i] (fp32) -> xnT8[b][i][c] (fp8, plain order)
__global__ void __launch_bounds__(256) norm_tr_kernel(const float* __restrict__ x,
                                                      const float* __restrict__ stats,
                                                      const float* __restrict__ nw,
                                                      const float* __restrict__ nb,
                                                      fp8_t* __restrict__ xnT8) {
  __shared__ float tile[64][65];   // [c_off][i_off]
  const int b  = blockIdx.z;
  const int i0 = blockIdx.x * 64;   // hw
  const int c0 = blockIdx.y * 64;   // channel
  const int tx = threadIdx.x & 63;
  const int ty = threadIdx.x >> 6;  // 0..3
  const int cbase = c0 + ty * 16;
  const int g = cbase >> 4;         // group const across r (16 channels per ty)
  const float inv = 1.f / (float)(CPG_ * HW_);
  const float sum  = stats[(b * G_ + g) * 2 + 0];
  const float ssum = stats[(b * G_ + g) * 2 + 1];
  const float mean = sum * inv;
  const float rstd = rsqrtf(ssum * inv - mean * mean + EPS_);
#pragma unroll
  for (int r = 0; r < 16; ++r) {
    const int c = cbase + r;
    float v = x[((size_t)b * C_ + c) * HW_ + i0 + tx];
    tile[ty * 16 + r][tx] = (v - mean) * rstd * nw[c] + nb[c];
  }
  __syncthreads();
  const int il = threadIdx.x >> 2;
  const int q4 = threadIdx.x & 3;
#pragma unroll
  for (int m = 0; m < 4; ++m) {
    const int cq = q4 + m * 4;     // 0..15
    u32 dw = 0;
    dw = (u32)__builtin_amdgcn_cvt_pk_fp8_f32(tile[cq * 4 + 0][il], tile[cq * 4 + 1][il], (int)dw, false);
    dw = (u32)__builtin_amdgcn_cvt_pk_fp8_f32(tile[cq * 4 + 2][il], tile[cq * 4 + 3][il], (int)dw, true);
    *(u32*)((unsigned char*)xnT8 + ((size_t)b * HW_ + i0 + il) * C_ + c0 + cq * 4) = dw;
  }
}

// ---------------- GEMM kernels ----------------

// Merged qk+v projections (saves a dispatch; v's small grid rides qk's tail).
// blocks [0,1024): QKt8[b][i][sig o] = fp8( xnT8 . wqkv8*2^-4 + bias )
// blocks [1024,1536): V8[b][c][sig j] = fp8( wqkv8_v*2^-4 . xnT8 + bias )
__global__ void __launch_bounds__(256, 2) qkv_gemm_kernel(const fp8_t* __restrict__ xnT8,
                                                          const fp8_t* __restrict__ wqkv8,
                                                          const float* __restrict__ qkv_b,
                                                          fp8_t* __restrict__ QKt8,
                                                          fp8_t* __restrict__ V8) {
  __shared__ __align__(16) unsigned char As[2 * 16384];
  __shared__ __align__(16) unsigned char Bs[2 * 16384];
  const int n = blockIdx.x;
  const int lane = threadIdx.x & 63, wave = threadIdx.x >> 6;
  const int wm = (wave >> 1) * 64, wn = (wave & 1) * 64;
  const int fr = lane & 15, q = lane >> 4;
  f32x4 acc[4][4]; zero_acc(acc);

  if (n < 1024) {
    const int xb = n & 7, yb = (n >> 3) & 31, b = n >> 8;
    const unsigned char* A  = (const unsigned char*)xnT8 + ((size_t)b * HW_ + yb * 128) * C_;
    const unsigned char* Bp = (const unsigned char*)wqkv8 + (size_t)xb * 128 * C_;
    gemm_bt_mx<false, 0x7F, 0x7B>(A, Bp, C_, C_, C_, acc, nullptr, As, Bs);
    const int r0 = yb * 128 + wm + (q << 2);
    const int cb = xb * 128 + wn;       // 64-col group base (true & stored)
    float bias[4];
#pragma unroll
    for (int j = 0; j < 4; ++j) bias[j] = qkv_b[cb + fr + j * 16];  // true cols
#pragma unroll
    for (int i = 0; i < 4; ++i)
#pragma unroll
      for (int r = 0; r < 4; ++r) {
        const int row = r0 + i * 16 + r;
        u32 dw = 0;
        dw = (u32)__builtin_amdgcn_cvt_pk_fp8_f32(acc[i][0][r] + bias[0],
                                                  acc[i][1][r] + bias[1], (int)dw, false);
        dw = (u32)__builtin_amdgcn_cvt_pk_fp8_f32(acc[i][2][r] + bias[2],
                                                  acc[i][3][r] + bias[3], (int)dw, true);
        *(u32*)((unsigned char*)QKt8 + ((size_t)b * HW_ + row) * 1024 + cb + fr * 4) = dw;
      }
  } else {
    const int m = n - 1024;
    const int xb = m & 31, yb = (m >> 5) & 3, b = m >> 7;
    const unsigned char* A  = (const unsigned char*)wqkv8 + (size_t)(1024 + yb * 128) * C_;
    const unsigned char* Bp = (const unsigned char*)xnT8 + ((size_t)b * HW_ + xb * 128) * C_;
    gemm_bt_mx<false, 0x7B, 0x7F>(A, Bp, C_, C_, C_, acc, nullptr, As, Bs);
    const int r0 = yb * 128 + wm + (q << 2);
    const int cb = xb * 128 + wn;       // hw 64-group base
#pragma unroll
    for (int i = 0; i < 4; ++i)
#pragma unroll
      for (int r = 0; r < 4; ++r) {
        const int row = r0 + i * 16 + r;        // c channel (row of V8)
        const float bias = qkv_b[1024 + row];
        u32 dw = 0;
        dw = (u32)__builtin_amdgcn_cvt_pk_fp8_f32(acc[i][0][r] + bias,
                                                  acc[i][1][r] + bias, (int)dw, false);
        dw = (u32)__builtin_amdgcn_cvt_pk_fp8_f32(acc[i][2][r] + bias,
                                                  acc[i][3][r] + bias, (int)dw, true);
        *(u32*)((unsigned char*)V8 + ((size_t)b * C_ + row) * HW_ + cb + fr * 4) = dw;
      }
  }
}

// P8[b][i][sigma-pos j] = fp8( 2^(scale*log2e * q_i.k_j - 4) ); MX-fp8 GEMM.
// XCD-aware 1-D grid: the 32 K-panel blocks sharing a Q row-panel are
// dispatch-adjacent on one XCD (QKt8 panels stay L2-hot per XCD).
__global__ void __launch_bounds__(256, 2) sexp_gemm_kernel(const fp8_t* __restrict__ QKt8,
                                                           fp8_t* __restrict__ P8) {
  __shared__ __align__(16) unsigned char As[2 * 16384];
  __shared__ __align__(16) unsigned char Bs[2 * 16384];
  const int n   = blockIdx.x;            // 4096 blocks
  const int xcd = n & 7;
  const int p   = n >> 3;                // 0..511 within XCD
  const int xb  = p & 31;                // K panel (fastest -> share Q panel)
  const int grp = xcd * 16 + (p >> 5);   // 0..127 = (yb, b) combo
  const int yb  = grp & 31;              // Q panel
  const int b   = grp >> 5;              // batch

  const unsigned char* QKtb = (const unsigned char*)QKt8 + (size_t)b * HW_ * 1024;
  fp8_t* Pb = P8 + (size_t)b * HW_ * HW_;
  f32x4 acc[4][4]; zero_acc(acc);
  const unsigned char* A  = QKtb + (size_t)yb * 128 * 1024;        // Q rows
  const unsigned char* Bp = QKtb + 512 + (size_t)xb * 128 * 1024;  // K rows
  gemm_bt_mx<false>(A, Bp, 512, 1024, 1024, acc, nullptr, As, Bs);
  const int lane = threadIdx.x & 63, wave = threadIdx.x >> 6;
  const int wm = (wave >> 1) * 64, wn = (wave & 1) * 64;
  const int fr = lane & 15, q = lane >> 4;
  const int r0 = yb * 128 + wm + (q << 2);
  const int cb = xb * 128 + wn;          // j 64-group base
#pragma unroll
  for (int i = 0; i < 4; ++i)
#pragma unroll
    for (int r = 0; r < 4; ++r) {
      const int row = r0 + i * 16 + r;
      float e0 = fexp2(fmaf(acc[i][0][r], SEXPC_, -4.0f));
      float e1 = fexp2(fmaf(acc[i][1][r], SEXPC_, -4.0f));
      float e2 = fexp2(fmaf(acc[i][2][r], SEXPC_, -4.0f));
      float e3 = fexp2(fmaf(acc[i][3][r], SEXPC_, -4.0f));
      u32 dw = 0;
      dw = (u32)__builtin_amdgcn_cvt_pk_fp8_f32(e0, e1, (int)dw, false);
      dw = (u32)__builtin_amdgcn_cvt_pk_fp8_f32(e2, e3, (int)dw, true);
      *(u32*)((unsigned char*)Pb + (size_t)row * HW_ + cb + fr * 4) = dw;
    }
}

// hmT8[b][i][sigma-pos c] = fp8( 16 * (sum_j P8 * V8) / rowsum(P8) )
// MX-fp8 GEMM with ones-MFMA row sums; XCD-aware block remap for P L2 reuse.
__global__ void __launch_bounds__(256, 2) pv_gemm_kernel(const fp8_t* __restrict__ P8,
                                                         const fp8_t* __restrict__ V8,
                                                         fp8_t* __restrict__ hmT8) {
  __shared__ __align__(16) unsigned char As[2 * 16384];
  __shared__ __align__(16) unsigned char Bs[2 * 16384];
  // decode swizzled block id: n = 512 blocks total
  const int n   = blockIdx.x;
  const int xcd = n & 7;           // XCD (round-robin heuristic)
  const int p   = n >> 3;          // 0..63, position within XCD
  const int xb  = p & 3;           // C panel (fastest -> adjacent blocks share P)
  const int grp = xcd * 16 + (p >> 2);  // 0..127 = (y,z) group
  const int yb  = grp & 31;        // HW panel
  const int b   = grp >> 5;        // batch

  const unsigned char* A  = (const unsigned char*)P8 + (size_t)b * HW_ * HW_ +
                            (size_t)yb * 128 * HW_;
  const unsigned char* Bp = (const unsigned char*)V8 + (size_t)b * C_ * HW_ +
                            (size_t)xb * 128 * HW_;
  fp8_t* hmTb = hmT8 + (size_t)b * HW_ * C_;

  f32x4 acc[4][4]; zero_acc(acc);
  f32x4 accl[4];
  {
    f32x4 z = {0.f, 0.f, 0.f, 0.f};
#pragma unroll
    for (int i = 0; i < 4; ++i) accl[i] = z;
  }
  gemm_bt_mx<true>(A, Bp, HW_, HW_, HW_, acc, accl, As, Bs);

  const int lane = threadIdx.x & 63, wave = threadIdx.x >> 6;
  const int wm = (wave >> 1) * 64, wn = (wave & 1) * 64;
  const int fr = lane & 15, q = lane >> 4;
  const int r0 = yb * 128 + wm + (q << 2);
  const int cb = xb * 128 + wn;   // c 64-group base (stored sigma-packed)
#pragma unroll
  for (int i = 0; i < 4; ++i)
#pragma unroll
    for (int r = 0; r < 4; ++r) {
      const int row = r0 + i * 16 + r;
      // x16 for fp8 range; undone by 2^-4 in proj. rcp: 1-ulp, fp8-invisible.
      const float rl = 16.f * __builtin_amdgcn_rcpf(accl[i][r]);
      u32 dw = 0;
      dw = (u32)__builtin_amdgcn_cvt_pk_fp8_f32(acc[i][0][r] * rl, acc[i][1][r] * rl, (int)dw, false);
      dw = (u32)__builtin_amdgcn_cvt_pk_fp8_f32(acc[i][2][r] * rl, acc[i][3][r] * rl, (int)dw, true);
      *(u32*)((unsigned char*)hmTb + (size_t)row * C_ + cb + fr * 4) = dw;
    }
}

// out[b][o][i] = x[b][o][i] + proj_b[o] + (wproj8*2^-4)(sigma) . (hmT8*2^-4)(sigma)
__global__ void __launch_bounds__(256, 2) proj_gemm_kernel(const fp8_t* __restrict__ wproj8,
                                                           const fp8_t* __restrict__ hmT8,
                                                           const float* __restrict__ proj_b,
                                                           const float* __restrict__ x,
                                                           float* __restrict__ out) {
  __shared__ __align__(16) unsigned char As[2 * 16384];
  __shared__ __align__(16) unsigned char Bs[2 * 16384];
  const int b = blockIdx.z;
  f32x4 acc[4][4]; zero_acc(acc);
  const unsigned char* A  = (const unsigned char*)wproj8 + (size_t)blockIdx.y * 128 * C_;
  const unsigned char* Bp = (const unsigned char*)hmT8 + ((size_t)b * HW_ + blockIdx.x * 128) * C_;
  gemm_bt_mx<false, 0x7B, 0x7B>(A, Bp, C_, C_, C_, acc, nullptr, As, Bs);
  const int lane = threadIdx.x & 63, wave = threadIdx.x >> 6;
  const int wm = (wave >> 1) * 64, wn = (wave & 1) * 64;
  const int r0 = blockIdx.y * 128 + wm + ((lane >> 4) << 2);
  const int c0 = blockIdx.x * 128 + wn + (lane & 15);
#pragma unroll
  for (int i = 0; i < 4; ++i)
#pragma unroll
    for (int r = 0; r < 4; ++r) {
      const int row = r0 + i * 16 + r;
      const float bias = proj_b[row];
#pragma unroll
      for (int j = 0; j < 4; ++j) {
        const int col = c0 + j * 16;
        const size_t idx = ((size_t)b * C_ + row) * HW_ + col;
        out[idx] = x[idx] + bias + acc[i][j][r];
      }
    }
}

// ---------------- launch ----------------
// Workspace layout (bytes), total ~110 MB:
//   wqkv8  fp8 [1536][512] (x16)         786,432
//   wproj8 fp8 [512][512] (x16, sigma)   262,144
//   stats  f32 [128][2]                    1,024
//   xnT8   fp8 [4][4096][512]          8,388,608
//   QKt8   fp8 [4][4096][1024](sig)   16,777,216
//   V8     fp8 [4][512][4096] (sig)    8,388,608
//   hmT8   fp8 [4][4096][512] (x16,sig) 8,388,608
//   P8     fp8 [4][4096][4096](sig)   67,108,864
extern "C" void kernel_launch(void* const* d_in, const int* in_sizes, int n_in,
                              void* d_out, int out_size, void* d_ws, size_t ws_size,
                              hipStream_t stream) {
  const float* x      = (const float*)d_in[0];
  const float* norm_w = (const float*)d_in[1];
  const float* norm_b = (const float*)d_in[2];
  const float* qkv_w  = (const float*)d_in[3];
  const float* qkv_b  = (const float*)d_in[4];
  const float* proj_w = (const float*)d_in[5];
  const float* proj_b = (const float*)d_in[6];
  float* out = (float*)d_out;

  char* ws = (char*)d_ws;
  size_t o = 0;
  fp8_t* wqkv8  = (fp8_t*)(ws + o); o += (size_t)1536 * 512;
  fp8_t* wproj8 = (fp8_t*)(ws + o); o += (size_t)512 * 512;
  float* stats  = (float*)(ws + o); o += 128 * 2 * 4;
  fp8_t* xnT8   = (fp8_t*)(ws + o); o += (size_t)B_ * HW_ * C_;
  fp8_t* QKt8   = (fp8_t*)(ws + o); o += (size_t)B_ * HW_ * 1024;
  fp8_t* V8     = (fp8_t*)(ws + o); o += (size_t)B_ * C_ * HW_;
  fp8_t* hmT8   = (fp8_t*)(ws + o); o += (size_t)B_ * HW_ * C_;
  fp8_t* P8     = (fp8_t*)(ws + o); o += (size_t)B_ * HW_ * HW_;

  hipMemsetAsync(stats, 0, 128 * 2 * sizeof(float), stream);
  prep_kernel<<<2048, 256, 0, stream>>>(x, stats, qkv_w, proj_w, wqkv8, wproj8);
  norm_tr_kernel<<<dim3(HW_ / 64, C_ / 64, B_), 256, 0, stream>>>(x, stats, norm_w, norm_b, xnT8);
  qkv_gemm_kernel<<<1536, 256, 0, stream>>>(xnT8, wqkv8, qkv_b, QKt8, V8);
  sexp_gemm_kernel<<<4096, 256, 0, stream>>>(QKt8, P8);
  pv_gemm_kernel<<<512, 256, 0, stream>>>(P8, V8, hmT8);
  proj_gemm_kernel<<<dim3(HW_ / 128, C_ / 128, B_), 256, 0, stream>>>(
      wproj8, hmT8, proj_b, x, out);
}

// Round 8
// 229.950 us; speedup vs baseline: 1.4712x; 1.4712x over previous
//
#include <hip/hip_runtime.h>
#include <hip/hip_fp8.h>
#include <cstdint>
#include <cmath>

// Problem constants
#define B_   4
#define C_   512
#define HW_  4096
#define G_   32
#define CPG_ 16
#define EPS_ 1e-6f
#define SCALE_ 0.04419417382415922f  // 1/sqrt(512)
#define PSCALE_ 0.0625f              // P pre-scale; cancels in acc/rowsum ratio
#define SEXPC_ 0.063758715306f       // SCALE * log2(e): exp(a*S)*2^-4 = 2^(a*SEXPC - 4)

// ---------------------------------------------------------------------------
// Column permutation (sigma): GEMM epilogues store outputs in the MFMA
// C-layout packed order. Within each 64-col group, stored position
// p = fr*4 + j holds true column c = j*16 + fr. Invariant under contraction
// as long as producer & consumer agree.
//
// Weight scaling: fp8 weights are stored x16; the MFMA e8m0 scale operand
// 0x7B (= 2^-4) folds the 1/16 back in HW. Same trick for hmT8.
//
// R16: resubmission of R15 (container infra failure, no kernel signal).
// R15 rationale: register-dbuf SPILLED (pv WRITE_SIZE 8->248 MB = scratch).
// Model: 2-phase K-step = 1104 cyc MFMA vs ~2900 cyc fixed overhead/SIMD.
// Can't hide it (R3/R5/R6 all failed) -> AMORTIZE it: sexp moves to a
// 256^2 tile, 512 threads, SAME proven 2-phase skeleton (stage-ahead +
// vmcnt(8) + 2 barriers), 32 MFMAs per barrier pair (2208 cyc/SIMD).
// b-fragments read in 2 dead-before-reload halves to cap live regs (~235).
// pv/qkv/proj stay on the verified R12 128^2 loop this round.
// ---------------------------------------------------------------------------

typedef __bf16 bf16_t;
typedef __bf16 bf16x8 __attribute__((ext_vector_type(8)));
typedef float  f32x4  __attribute__((ext_vector_type(4)));
typedef int    i32x4  __attribute__((ext_vector_type(4)));
typedef int    i32x8  __attribute__((ext_vector_type(8)));
typedef unsigned int u32;
typedef __hip_fp8_e4m3 fp8_t;  // OCP e4m3fn on gfx950

// Async global->LDS copy, 16B per lane. LDS dest is wave-uniform base + lane*16.
__device__ __forceinline__ void cp16(const void* g, void* l) {
  __builtin_amdgcn_global_load_lds((__attribute__((address_space(1))) u32*)(g),
                                   (__attribute__((address_space(3))) u32*)(l),
                                   16, 0, 0);
}

// Raw v_exp_f32 (2^x). s_nop 1 covers the trans->consumer wait-state
// conservatively (inline asm is opaque to the hazard recognizer).
__device__ __forceinline__ float fexp2(float x) {
  float r;
  asm("v_exp_f32 %0, %1\n\ts_nop 1" : "=v"(r) : "v"(x));
  return r;
}

__device__ __forceinline__ void zero_acc(f32x4 acc[4][4]) {
  f32x4 z = {0.f, 0.f, 0.f, 0.f};
#pragma unroll
  for (int i = 0; i < 4; ++i)
#pragma unroll
    for (int j = 0; j < 4; ++j) acc[i][j] = z;
}

// MX-fp8 BT GEMM mainloop (BK=128): mfma_scale_f32_16x16x128_f8f6f4, fmt 0
// (e4m3), per-operand e8m0 scales SA/SB (0x7F = 1.0, 0x7B = 2^-4).
// LDS rows are 128 B (8 chunks); chunk-rotation swizzle mod 8 keeps staging
// and the paired ds_read_b128 fragment reads at the LDS bank floor.
// Double-buffered (2x16 KB per operand, caller-provided LDS), counted vmcnt.
template <bool ROWSUM, int SA = 0x7F, int SB = 0x7F>
__device__ __forceinline__ void gemm_bt_mx(const unsigned char* __restrict__ A,
                                           const unsigned char* __restrict__ B,
                                           int K, int lda, int ldb,
                                           f32x4 acc[4][4], f32x4 accl[4],
                                           unsigned char* AsB, unsigned char* BsB) {
  const int tid  = threadIdx.x;
  const int wave = tid >> 6;
  const int lane = tid & 63;
  const int wm = (wave >> 1) * 64;
  const int wn = (wave & 1) * 64;
  // staging: per cp16 call lane covers row (lane>>3), LDS chunk (lane&7);
  // rotation: LDS chunk c of row r holds global chunk (c - r) & 7.
  const int srow = lane >> 3;
  const int gch  = ((lane & 7) - srow) & 7;
  const unsigned char* gA = A + (size_t)(wave * 32 + srow) * lda + gch * 16;
  const unsigned char* gB = B + (size_t)(wave * 32 + srow) * ldb + gch * 16;
  const int lofs = wave * 32 * 128;
  const int fr = lane & 15;
  const int q  = lane >> 4;
  // lane wants global chunks 2q, 2q+1 of its row (32 B = K-128 fragment)
  const int co0 = ((2 * q     + fr) & 7) * 16;
  const int co1 = ((2 * q + 1 + fr) & 7) * 16;
  const i32x8 vones = {0x38383838, 0x38383838, 0x38383838, 0x38383838,
                       0x38383838, 0x38383838, 0x38383838, 0x38383838};

  const int nT = K >> 7;
  // prologue: stage tile 0 into buffer 0
#pragma unroll
  for (int cc = 0; cc < 4; ++cc) {
    cp16(gA + (size_t)(cc * 8) * lda, AsB + lofs + cc * 1024);
    cp16(gB + (size_t)(cc * 8) * ldb, BsB + lofs + cc * 1024);
  }
  gA += 128; gB += 128;

#pragma unroll 1
  for (int t = 0; t < nT; ++t) {
    const int cur = t & 1;
    if (t + 1 < nT) {
      // stage tile t+1 into the other buffer; it flies across this tile's
      // compute and is drained by next iteration's vmcnt(8).
#pragma unroll
      for (int cc = 0; cc < 4; ++cc) {
        cp16(gA + (size_t)(cc * 8) * lda, AsB + (cur ^ 1) * 16384 + lofs + cc * 1024);
        cp16(gB + (size_t)(cc * 8) * ldb, BsB + (cur ^ 1) * 16384 + lofs + cc * 1024);
      }
      gA += 128; gB += 128;
      asm volatile("s_waitcnt vmcnt(8)" ::: "memory");  // tile t resident
    } else {
      asm volatile("s_waitcnt vmcnt(0)" ::: "memory");  // last tile resident
    }
    __builtin_amdgcn_s_barrier();   // tile t visible to all waves

    i32x8 a[4], b[4];
    const unsigned char* Ab = AsB + cur * 16384;
    const unsigned char* Bb = BsB + cur * 16384;
#pragma unroll
    for (int i = 0; i < 4; ++i) {
      const int ro = (wm + i * 16 + fr) * 128;
      i32x4 lo = *(const i32x4*)(Ab + ro + co0);
      i32x4 hi = *(const i32x4*)(Ab + ro + co1);
      a[i] = __builtin_shufflevector(lo, hi, 0, 1, 2, 3, 4, 5, 6, 7);
    }
#pragma unroll
    for (int j = 0; j < 4; ++j) {
      const int ro = (wn + j * 16 + fr) * 128;
      i32x4 lo = *(const i32x4*)(Bb + ro + co0);
      i32x4 hi = *(const i32x4*)(Bb + ro + co1);
      b[j] = __builtin_shufflevector(lo, hi, 0, 1, 2, 3, 4, 5, 6, 7);
    }
    __builtin_amdgcn_s_setprio(1);
#pragma unroll
    for (int i = 0; i < 4; ++i) {
#pragma unroll
      for (int j = 0; j < 4; ++j)
        acc[i][j] = __builtin_amdgcn_mfma_scale_f32_16x16x128_f8f6f4(
            a[i], b[j], acc[i][j], 0, 0, 0, SA, 0, SB);
      if (ROWSUM)
        accl[i] = __builtin_amdgcn_mfma_scale_f32_16x16x128_f8f6f4(
            a[i], vones, accl[i], 0, 0, 0, SA, 0, 0x7F);
    }
    __builtin_amdgcn_s_setprio(0);
    __builtin_amdgcn_s_barrier();   // all reads of buf[cur] done
  }
}

// ---------------- prep: GroupNorm partials + weight casts (merged) ----------

// blocks [0,1024): partial GN stats (8 hw-chunks per group, 2 atomics each).
// blocks [1024,2048): wqkv8 = fp8(qkv_w*16) plain; wproj8 = fp8(proj_w*16)
// with sigma-permuted c columns.
__global__ void __launch_bounds__(256) prep_kernel(const float* __restrict__ x,
                                                   float* __restrict__ stats,
                                                   const float* __restrict__ qkv_w,
                                                   const float* __restrict__ proj_w,
                                                   fp8_t* __restrict__ wqkv8,
                                                   fp8_t* __restrict__ wproj8) {
  __shared__ float rs[256], rss[256];
  const int n = blockIdx.x;
  if (n < 1024) {
    const int bg = n >> 3;       // group id 0..127
    const int ch = n & 7;        // hw chunk 0..7
    const float4* base = (const float4*)(x + (size_t)bg * (CPG_ * HW_)) +
                         (size_t)ch * (CPG_ * HW_ / 4 / 8);
    float s = 0.f, ss = 0.f;
    for (int i = threadIdx.x; i < CPG_ * HW_ / 4 / 8; i += 256) {
      float4 v = base[i];
      s  += v.x + v.y + v.z + v.w;
      ss += v.x * v.x + v.y * v.y + v.z * v.z + v.w * v.w;
    }
    rs[threadIdx.x] = s; rss[threadIdx.x] = ss;
    __syncthreads();
    for (int st = 128; st > 0; st >>= 1) {
      if ((int)threadIdx.x < st) {
        rs[threadIdx.x]  += rs[threadIdx.x + st];
        rss[threadIdx.x] += rss[threadIdx.x + st];
      }
      __syncthreads();
    }
    if (threadIdx.x == 0) {
      atomicAdd(&stats[bg * 2 + 0], rs[0]);
      atomicAdd(&stats[bg * 2 + 1], rss[0]);
    }
  } else {
    const int idx = (n - 1024) * 256 + threadIdx.x;   // quad index
    const int t = idx * 4;
    const int nq = 1536 * 512;
    if (t < nq) {
      u32 dw = 0;
      dw = (u32)__builtin_amdgcn_cvt_pk_fp8_f32(qkv_w[t] * 16.f, qkv_w[t + 1] * 16.f, (int)dw, false);
      dw = (u32)__builtin_amdgcn_cvt_pk_fp8_f32(qkv_w[t + 2] * 16.f, qkv_w[t + 3] * 16.f, (int)dw, true);
      *(u32*)((unsigned char*)wqkv8 + t) = dw;
    } else {
      const int tt = t - nq;          // o*512 + p, p multiple of 4
      const int o = tt >> 9;
      const int p = tt & 511;
      float v[4];
#pragma unroll
      for (int e = 0; e < 4; ++e) {
        const int pe = p + e;
        const int off = pe & 63;
        const int c = (pe & ~63) + ((off & 3) << 4) + (off >> 2);  // sigma(pe)
        v[e] = proj_w[(o << 9) + c] * 16.f;
      }
      u32 dw = 0;
      dw = (u32)__builtin_amdgcn_cvt_pk_fp8_f32(v[0], v[1], (int)dw, false);
      dw = (u32)__builtin_amdgcn_cvt_pk_fp8_f32(v[2], v[3], (int)dw, true);
      *(u32*)((unsigned char*)wproj8 + tt) = dw;
    }
  }
}

// normalize + transpose: x[b][c][i] (fp32) -> xnT8[b][i][c] (fp8, plain order)
__global__ void __launch_bounds__(256) norm_tr_kernel(const float* __restrict__ x,
                                                      const float* __restrict__ stats,
                                                      const float* __restrict__ nw,
                                                      const float* __restrict__ nb,
                                                      fp8_t* __restrict__ xnT8) {
  __shared__ float tile[64][65];   // [c_off][i_off]
  const int b  = blockIdx.z;
  const int i0 = blockIdx.x * 64;   // hw
  const int c0 = blockIdx.y * 64;   // channel
  const int tx = threadIdx.x & 63;
  const int ty = threadIdx.x >> 6;  // 0..3
  const int cbase = c0 + ty * 16;
  const int g = cbase >> 4;         // group const across r (16 channels per ty)
  const float inv = 1.f / (float)(CPG_ * HW_);
  const float sum  = stats[(b * G_ + g) * 2 + 0];
  const float ssum = stats[(b * G_ + g) * 2 + 1];
  const float mean = sum * inv;
  const float rstd = rsqrtf(ssum * inv - mean * mean + EPS_);
#pragma unroll
  for (int r = 0; r < 16; ++r) {
    const int c = cbase + r;
    float v = x[((size_t)b * C_ + c) * HW_ + i0 + tx];
    tile[ty * 16 + r][tx] = (v - mean) * rstd * nw[c] + nb[c];
  }
  __syncthreads();
  const int il = threadIdx.x >> 2;
  const int q4 = threadIdx.x & 3;
#pragma unroll
  for (int m = 0; m < 4; ++m) {
    const int cq = q4 + m * 4;     // 0..15
    u32 dw = 0;
    dw = (u32)__builtin_amdgcn_cvt_pk_fp8_f32(tile[cq * 4 + 0][il], tile[cq * 4 + 1][il], (int)dw, false);
    dw = (u32)__builtin_amdgcn_cvt_pk_fp8_f32(tile[cq * 4 + 2][il], tile[cq * 4 + 3][il], (int)dw, true);
    *(u32*)((unsigned char*)xnT8 + ((size_t)b * HW_ + i0 + il) * C_ + c0 + cq * 4) = dw;
  }
}

// ---------------- GEMM kernels ----------------

// Merged qk+v projections (saves a dispatch; v's small grid rides qk's tail).
// blocks [0,1024): QKt8[b][i][sig o] = fp8( xnT8 . wqkv8*2^-4 + bias )
// blocks [1024,1536): V8[b][c][sig j] = fp8( wqkv8_v*2^-4 . xnT8 + bias )
__global__ void __launch_bounds__(256) qkv_gemm_kernel(const fp8_t* __restrict__ xnT8,
                                                       const fp8_t* __restrict__ wqkv8,
                                                       const float* __restrict__ qkv_b,
                                                       fp8_t* __restrict__ QKt8,
                                                       fp8_t* __restrict__ V8) {
  __shared__ __align__(16) unsigned char As[2 * 16384];
  __shared__ __align__(16) unsigned char Bs[2 * 16384];
  const int n = blockIdx.x;
  const int lane = threadIdx.x & 63, wave = threadIdx.x >> 6;
  const int wm = (wave >> 1) * 64, wn = (wave & 1) * 64;
  const int fr = lane & 15, q = lane >> 4;
  f32x4 acc[4][4]; zero_acc(acc);

  if (n < 1024) {
    const int xb = n & 7, yb = (n >> 3) & 31, b = n >> 8;
    const unsigned char* A  = (const unsigned char*)xnT8 + ((size_t)b * HW_ + yb * 128) * C_;
    const unsigned char* Bp = (const unsigned char*)wqkv8 + (size_t)xb * 128 * C_;
    gemm_bt_mx<false, 0x7F, 0x7B>(A, Bp, C_, C_, C_, acc, nullptr, As, Bs);
    const int r0 = yb * 128 + wm + (q << 2);
    const int cb = xb * 128 + wn;       // 64-col group base (true & stored)
    float bias[4];
#pragma unroll
    for (int j = 0; j < 4; ++j) bias[j] = qkv_b[cb + fr + j * 16];  // true cols
#pragma unroll
    for (int i = 0; i < 4; ++i)
#pragma unroll
      for (int r = 0; r < 4; ++r) {
        const int row = r0 + i * 16 + r;
        u32 dw = 0;
        dw = (u32)__builtin_amdgcn_cvt_pk_fp8_f32(acc[i][0][r] + bias[0],
                                                  acc[i][1][r] + bias[1], (int)dw, false);
        dw = (u32)__builtin_amdgcn_cvt_pk_fp8_f32(acc[i][2][r] + bias[2],
                                                  acc[i][3][r] + bias[3], (int)dw, true);
        *(u32*)((unsigned char*)QKt8 + ((size_t)b * HW_ + row) * 1024 + cb + fr * 4) = dw;
      }
  } else {
    const int m = n - 1024;
    const int xb = m & 31, yb = (m >> 5) & 3, b = m >> 7;
    const unsigned char* A  = (const unsigned char*)wqkv8 + (size_t)(1024 + yb * 128) * C_;
    const unsigned char* Bp = (const unsigned char*)xnT8 + ((size_t)b * HW_ + xb * 128) * C_;
    gemm_bt_mx<false, 0x7B, 0x7F>(A, Bp, C_, C_, C_, acc, nullptr, As, Bs);
    const int r0 = yb * 128 + wm + (q << 2);
    const int cb = xb * 128 + wn;       // hw 64-group base
#pragma unroll
    for (int i = 0; i < 4; ++i)
#pragma unroll
      for (int r = 0; r < 4; ++r) {
        const int row = r0 + i * 16 + r;        // c channel (row of V8)
        const float bias = qkv_b[1024 + row];
        u32 dw = 0;
        dw = (u32)__builtin_amdgcn_cvt_pk_fp8_f32(acc[i][0][r] + bias,
                                                  acc[i][1][r] + bias, (int)dw, false);
        dw = (u32)__builtin_amdgcn_cvt_pk_fp8_f32(acc[i][2][r] + bias,
                                                  acc[i][3][r] + bias, (int)dw, true);
        *(u32*)((unsigned char*)V8 + ((size_t)b * C_ + row) * HW_ + cb + fr * 4) = dw;
      }
  }
}

// P8[b][i][sigma-pos j] = fp8( 2^(scale*log2e * q_i.k_j - 4) )
// 256^2-tile 2-PHASE MX-fp8 GEMM: 1024 blocks, 8 waves (wave grid 2x4,
// per-wave 128x64, acc[8][4]). Per K-step (BK=128): stage tile t+1 (8 cp16)
// -> vmcnt(8) -> barrier -> ds_read a[8],b01 -> 16 MFMA -> ds_read b23 ->
// 16 MFMA -> barrier. 32 MFMAs (2208 cyc/SIMD) amortize the same per-step
// overhead that capped the 128^2 loop at ~24% MfmaUtil. b-frags read in two
// dead-before-reload halves to cap live registers (~235 < 256 @ (512,2)).
__global__ void __launch_bounds__(512, 2) sexp_gemm_kernel(const fp8_t* __restrict__ QKt8,
                                                           fp8_t* __restrict__ P8) {
  __shared__ __align__(16) unsigned char As[2][256 * 128];
  __shared__ __align__(16) unsigned char Bs[2][256 * 128];

  // XCD-aware decode: 16 xb (K col panels) fastest within an XCD so blocks
  // sharing a Q row-panel are co-resident on one XCD's L2.
  const int n   = blockIdx.x;           // 1024 blocks
  const int xcd = n & 7;
  const int p   = n >> 3;               // 0..127
  const int xb  = p & 15;               // K col panel (256 wide)
  const int grp = xcd * 8 + (p >> 4);   // 0..63 = (yb, b)
  const int yb  = grp & 15;             // Q row panel (256 tall)
  const int b   = grp >> 4;             // batch

  const unsigned char* QKtb = (const unsigned char*)QKt8 + (size_t)b * HW_ * 1024;
  const unsigned char* Agl = QKtb + (size_t)yb * 256 * 1024;        // Q rows
  const unsigned char* Bgl = QKtb + 512 + (size_t)xb * 256 * 1024;  // K rows

  const int tid  = threadIdx.x;
  const int lane = tid & 63;
  const int wave = tid >> 6;            // 0..7
  const int wm   = (wave >> 2) * 128;   // row half
  const int wn   = (wave & 3) * 64;     // col quarter
  const int fr   = lane & 15;
  const int q    = lane >> 4;
  const int co0  = ((2 * q     + fr) & 7) * 16;
  const int co1  = ((2 * q + 1 + fr) & 7) * 16;

  // staging: 512 threads cover 64 rows x 8 chunks per sweep; 4 sweeps per
  // operand tile. chunk-rotation mod 8 (row mod 8 = srow mod 8, same
  // invariant as the 128^2 loop so co0/co1 formulas carry over).
  const int srow = tid >> 3;            // 0..63
  const int sch  = tid & 7;
  const int gch  = ((sch - srow) & 7) * 16;

  f32x4 acc[8][4];
  {
    f32x4 z = {0.f, 0.f, 0.f, 0.f};
#pragma unroll
    for (int i = 0; i < 8; ++i)
#pragma unroll
      for (int j = 0; j < 4; ++j) acc[i][j] = z;
  }

  // prologue: stage tile 0 (8 cp16/thread)
#pragma unroll
  for (int s = 0; s < 4; ++s) {
    const int row = s * 64 + srow;
    cp16(Agl + (size_t)row * 1024 + gch, &As[0][row * 128 + sch * 16]);
    cp16(Bgl + (size_t)row * 1024 + gch, &Bs[0][row * 128 + sch * 16]);
  }

#pragma unroll 1
  for (int t = 0; t < 4; ++t) {
    const int cur = t & 1;
    if (t < 3) {
      // stage tile t+1; drained by NEXT iteration's vmcnt(8)
#pragma unroll
      for (int s = 0; s < 4; ++s) {
        const int row = s * 64 + srow;
        cp16(Agl + (size_t)row * 1024 + (t + 1) * 128 + gch,
             &As[cur ^ 1][row * 128 + sch * 16]);
        cp16(Bgl + (size_t)row * 1024 + (t + 1) * 128 + gch,
             &Bs[cur ^ 1][row * 128 + sch * 16]);
      }
      asm volatile("s_waitcnt vmcnt(8)" ::: "memory");  // tile t resident
    } else {
      asm volatile("s_waitcnt vmcnt(0)" ::: "memory");
    }
    __builtin_amdgcn_s_barrier();   // tile t visible to all waves

    const unsigned char* Ab = As[cur];
    const unsigned char* Bb = Bs[cur];
    i32x8 a[8];
#pragma unroll
    for (int i = 0; i < 8; ++i) {
      const int ro = (wm + i * 16 + fr) * 128;
      i32x4 lo = *(const i32x4*)(Ab + ro + co0);
      i32x4 hi = *(const i32x4*)(Ab + ro + co1);
      a[i] = __builtin_shufflevector(lo, hi, 0, 1, 2, 3, 4, 5, 6, 7);
    }
    i32x8 b01[2];
#pragma unroll
    for (int j = 0; j < 2; ++j) {
      const int ro = (wn + j * 16 + fr) * 128;
      i32x4 lo = *(const i32x4*)(Bb + ro + co0);
      i32x4 hi = *(const i32x4*)(Bb + ro + co1);
      b01[j] = __builtin_shufflevector(lo, hi, 0, 1, 2, 3, 4, 5, 6, 7);
    }
    __builtin_amdgcn_s_setprio(1);
#pragma unroll
    for (int i = 0; i < 8; ++i)
#pragma unroll
      for (int j = 0; j < 2; ++j)
        acc[i][j] = __builtin_amdgcn_mfma_scale_f32_16x16x128_f8f6f4(
            a[i], b01[j], acc[i][j], 0, 0, 0, 0x7F, 0, 0x7F);
    // second b half (b01 now dead; allocator reuses its registers)
    i32x8 b23[2];
#pragma unroll
    for (int j = 0; j < 2; ++j) {
      const int ro = (wn + (j + 2) * 16 + fr) * 128;
      i32x4 lo = *(const i32x4*)(Bb + ro + co0);
      i32x4 hi = *(const i32x4*)(Bb + ro + co1);
      b23[j] = __builtin_shufflevector(lo, hi, 0, 1, 2, 3, 4, 5, 6, 7);
    }
#pragma unroll
    for (int i = 0; i < 8; ++i)
#pragma unroll
      for (int j = 0; j < 2; ++j)
        acc[i][j + 2] = __builtin_amdgcn_mfma_scale_f32_16x16x128_f8f6f4(
            a[i], b23[j], acc[i][j + 2], 0, 0, 0, 0x7F, 0, 0x7F);
    __builtin_amdgcn_s_setprio(0);
    __builtin_amdgcn_s_barrier();   // all reads of buf[cur] done
  }

  // epilogue: exp2-fold + fp8 pack, sigma-packed 64-col groups
  fp8_t* Pb = P8 + (size_t)b * HW_ * HW_;
  const int r0 = yb * 256 + wm + (q << 2);
  const int cb = xb * 256 + wn;
#pragma unroll
  for (int i = 0; i < 8; ++i)
#pragma unroll
    for (int r = 0; r < 4; ++r) {
      const int row = r0 + i * 16 + r;
      float e0 = fexp2(fmaf(acc[i][0][r], SEXPC_, -4.0f));
      float e1 = fexp2(fmaf(acc[i][1][r], SEXPC_, -4.0f));
      float e2 = fexp2(fmaf(acc[i][2][r], SEXPC_, -4.0f));
      float e3 = fexp2(fmaf(acc[i][3][r], SEXPC_, -4.0f));
      u32 dw = 0;
      dw = (u32)__builtin_amdgcn_cvt_pk_fp8_f32(e0, e1, (int)dw, false);
      dw = (u32)__builtin_amdgcn_cvt_pk_fp8_f32(e2, e3, (int)dw, true);
      *(u32*)((unsigned char*)Pb + (size_t)row * HW_ + cb + fr * 4) = dw;
    }
}

// hmT8[b][i][sigma-pos c] = fp8( 16 * (sum_j P8 * V8) / rowsum(P8) )
// MX-fp8 GEMM with ones-MFMA row sums; XCD-aware block remap for P L2 reuse.
__global__ void __launch_bounds__(256) pv_gemm_kernel(const fp8_t* __restrict__ P8,
                                                      const fp8_t* __restrict__ V8,
                                                      fp8_t* __restrict__ hmT8) {
  __shared__ __align__(16) unsigned char As[2 * 16384];
  __shared__ __align__(16) unsigned char Bs[2 * 16384];
  // decode swizzled block id: n = 512 blocks total
  const int n   = blockIdx.x;
  const int xcd = n & 7;           // XCD (round-robin heuristic)
  const int p   = n >> 3;          // 0..63, position within XCD
  const int xb  = p & 3;           // C panel (fastest -> adjacent blocks share P)
  const int grp = xcd * 16 + (p >> 2);  // 0..127 = (y,z) group
  const int yb  = grp & 31;        // HW panel
  const int b   = grp >> 5;        // batch

  const unsigned char* A  = (const unsigned char*)P8 + (size_t)b * HW_ * HW_ +
                            (size_t)yb * 128 * HW_;
  const unsigned char* Bp = (const unsigned char*)V8 + (size_t)b * C_ * HW_ +
                            (size_t)xb * 128 * HW_;
  fp8_t* hmTb = hmT8 + (size_t)b * HW_ * C_;

  f32x4 acc[4][4]; zero_acc(acc);
  f32x4 accl[4];
  {
    f32x4 z = {0.f, 0.f, 0.f, 0.f};
#pragma unroll
    for (int i = 0; i < 4; ++i) accl[i] = z;
  }
  gemm_bt_mx<true>(A, Bp, HW_, HW_, HW_, acc, accl, As, Bs);

  const int lane = threadIdx.x & 63, wave = threadIdx.x >> 6;
  const int wm = (wave >> 1) * 64, wn = (wave & 1) * 64;
  const int fr = lane & 15, q = lane >> 4;
  const int r0 = yb * 128 + wm + (q << 2);
  const int cb = xb * 128 + wn;   // c 64-group base (stored sigma-packed)
#pragma unroll
  for (int i = 0; i < 4; ++i)
#pragma unroll
    for (int r = 0; r < 4; ++r) {
      const int row = r0 + i * 16 + r;
      // x16 for fp8 range; undone by 2^-4 in proj. rcp: 1-ulp, fp8-invisible.
      const float rl = 16.f * __builtin_amdgcn_rcpf(accl[i][r]);
      u32 dw = 0;
      dw = (u32)__builtin_amdgcn_cvt_pk_fp8_f32(acc[i][0][r] * rl, acc[i][1][r] * rl, (int)dw, false);
      dw = (u32)__builtin_amdgcn_cvt_pk_fp8_f32(acc[i][2][r] * rl, acc[i][3][r] * rl, (int)dw, true);
      *(u32*)((unsigned char*)hmTb + (size_t)row * C_ + cb + fr * 4) = dw;
    }
}

// out[b][o][i] = x[b][o][i] + proj_b[o] + (wproj8*2^-4)(sigma) . (hmT8*2^-4)(sigma)
__global__ void __launch_bounds__(256) proj_gemm_kernel(const fp8_t* __restrict__ wproj8,
                                                        const fp8_t* __restrict__ hmT8,
                                                        const float* __restrict__ proj_b,
                                                        const float* __restrict__ x,
                                                        float* __restrict__ out) {
  __shared__ __align__(16) unsigned char As[2 * 16384];
  __shared__ __align__(16) unsigned char Bs[2 * 16384];
  const int b = blockIdx.z;
  f32x4 acc[4][4]; zero_acc(acc);
  const unsigned char* A  = (const unsigned char*)wproj8 + (size_t)blockIdx.y * 128 * C_;
  const unsigned char* Bp = (const unsigned char*)hmT8 + ((size_t)b * HW_ + blockIdx.x * 128) * C_;
  gemm_bt_mx<false, 0x7B, 0x7B>(A, Bp, C_, C_, C_, acc, nullptr, As, Bs);
  const int lane = threadIdx.x & 63, wave = threadIdx.x >> 6;
  const int wm = (wave >> 1) * 64, wn = (wave & 1) * 64;
  const int r0 = blockIdx.y * 128 + wm + ((lane >> 4) << 2);
  const int c0 = blockIdx.x * 128 + wn + (lane & 15);
#pragma unroll
  for (int i = 0; i < 4; ++i)
#pragma unroll
    for (int r = 0; r < 4; ++r) {
      const int row = r0 + i * 16 + r;
      const float bias = proj_b[row];
#pragma unroll
      for (int j = 0; j < 4; ++j) {
        const int col = c0 + j * 16;
        const size_t idx = ((size_t)b * C_ + row) * HW_ + col;
        out[idx] = x[idx] + bias + acc[i][j][r];
      }
    }
}

// ---------------- launch ----------------
// Workspace layout (bytes), total ~110 MB:
//   wqkv8  fp8 [1536][512] (x16)         786,432
//   wproj8 fp8 [512][512] (x16, sigma)   262,144
//   stats  f32 [128][2]                    1,024
//   xnT8   fp8 [4][4096][512]          8,388,608
//   QKt8   fp8 [4][4096][1024](sig)   16,777,216
//   V8     fp8 [4][512][4096] (sig)    8,388,608
//   hmT8   fp8 [4][4096][512] (x16,sig) 8,388,608
//   P8     fp8 [4][4096][4096](sig)   67,108,864
extern "C" void kernel_launch(void* const* d_in, const int* in_sizes, int n_in,
                              void* d_out, int out_size, void* d_ws, size_t ws_size,
                              hipStream_t stream) {
  const float* x      = (const float*)d_in[0];
  const float* norm_w = (const float*)d_in[1];
  const float* norm_b = (const float*)d_in[2];
  const float* qkv_w  = (const float*)d_in[3];
  const float* qkv_b  = (const float*)d_in[4];
  const float* proj_w = (const float*)d_in[5];
  const float* proj_b = (const float*)d_in[6];
  float* out = (float*)d_out;

  char* ws = (char*)d_ws;
  size_t o = 0;
  fp8_t* wqkv8  = (fp8_t*)(ws + o); o += (size_t)1536 * 512;
  fp8_t* wproj8 = (fp8_t*)(ws + o); o += (size_t)512 * 512;
  float* stats  = (float*)(ws + o); o += 128 * 2 * 4;
  fp8_t* xnT8   = (fp8_t*)(ws + o); o += (size_t)B_ * HW_ * C_;
  fp8_t* QKt8   = (fp8_t*)(ws + o); o += (size_t)B_ * HW_ * 1024;
  fp8_t* V8     = (fp8_t*)(ws + o); o += (size_t)B_ * C_ * HW_;
  fp8_t* hmT8   = (fp8_t*)(ws + o); o += (size_t)B_ * HW_ * C_;
  fp8_t* P8     = (fp8_t*)(ws + o); o += (size_t)B_ * HW_ * HW_;

  hipMemsetAsync(stats, 0, 128 * 2 * sizeof(float), stream);
  prep_kernel<<<2048, 256, 0, stream>>>(x, stats, qkv_w, proj_w, wqkv8, wproj8);
  norm_tr_kernel<<<dim3(HW_ / 64, C_ / 64, B_), 256, 0, stream>>>(x, stats, norm_w, norm_b, xnT8);
  qkv_gemm_kernel<<<1536, 256, 0, stream>>>(xnT8, wqkv8, qkv_b, QKt8, V8);
  sexp_gemm_kernel<<<1024, 512, 0, stream>>>(QKt8, P8);
  pv_gemm_kernel<<<512, 256, 0, stream>>>(P8, V8, hmT8);
  proj_gemm_kernel<<<dim3(HW_ / 128, C_ / 128, B_), 256, 0, stream>>>(
      wproj8, hmT8, proj_b, x, out);
}

// Round 9
// 227.681 us; speedup vs baseline: 1.4858x; 1.0100x over previous
//
#include <hip/hip_runtime.h>
#include <hip/hip_fp8.h>
#include <cstdint>
#include <cmath>

// Problem constants
#define B_   4
#define C_   512
#define HW_  4096
#define G_   32
#define CPG_ 16
#define EPS_ 1e-6f
#define SCALE_ 0.04419417382415922f  // 1/sqrt(512)
#define PSCALE_ 0.0625f              // P pre-scale; cancels in acc/rowsum ratio
#define SEXPC_ 0.063758715306f       // SCALE * log2(e): exp(a*S)*2^-4 = 2^(a*SEXPC - 4)

// ---------------------------------------------------------------------------
// Column permutation (sigma): GEMM epilogues store outputs in the MFMA
// C-layout packed order. Within each 64-col group, stored position
// p = fr*4 + j holds true column c = j*16 + fr. Invariant under contraction
// as long as producer & consumer agree.
//
// Weight scaling: fp8 weights are stored x16; the MFMA e8m0 scale operand
// 0x7B (= 2^-4) folds the 1/16 back in HW. Same trick for hmT8.
//
// R17 (post-mortem R16): 256^2 2-phase sexp = 53.3us @ MfmaUtil 24% ==
// 128^2 (54.3 @ 24%). With R0/R3 (buffering/occupancy null), R5 (finer
// phases regress), R6 (reg-dbuf spills): every pipe sits at ~25% in strict
// rotation and no source-level schedule changes it. GEMM family is at its
// practical floor for these shapes. This round: housekeeping + L2 heat.
//  1. atomic-free GN stats (stats[128][8][2], no memset dispatch).
//  2. pv reads P panels in REVERSE within-XCD order: sexp pins each (yb,b)
//     panel's production to xcd=(b*32+yb)>>4; L2 retains the last ~8
//     512KB panels, so pv consumes hottest-first.
//  3. sexp stays on the 128^2 path (equal speed, 12 vs 31 MB FETCH).
// ---------------------------------------------------------------------------

typedef __bf16 bf16_t;
typedef __bf16 bf16x8 __attribute__((ext_vector_type(8)));
typedef float  f32x4  __attribute__((ext_vector_type(4)));
typedef int    i32x4  __attribute__((ext_vector_type(4)));
typedef int    i32x8  __attribute__((ext_vector_type(8)));
typedef unsigned int u32;
typedef __hip_fp8_e4m3 fp8_t;  // OCP e4m3fn on gfx950

// Async global->LDS copy, 16B per lane. LDS dest is wave-uniform base + lane*16.
__device__ __forceinline__ void cp16(const void* g, void* l) {
  __builtin_amdgcn_global_load_lds((__attribute__((address_space(1))) u32*)(g),
                                   (__attribute__((address_space(3))) u32*)(l),
                                   16, 0, 0);
}

// Raw v_exp_f32 (2^x). s_nop 1 covers the trans->consumer wait-state
// conservatively (inline asm is opaque to the hazard recognizer).
__device__ __forceinline__ float fexp2(float x) {
  float r;
  asm("v_exp_f32 %0, %1\n\ts_nop 1" : "=v"(r) : "v"(x));
  return r;
}

__device__ __forceinline__ void zero_acc(f32x4 acc[4][4]) {
  f32x4 z = {0.f, 0.f, 0.f, 0.f};
#pragma unroll
  for (int i = 0; i < 4; ++i)
#pragma unroll
    for (int j = 0; j < 4; ++j) acc[i][j] = z;
}

// MX-fp8 BT GEMM mainloop (BK=128): mfma_scale_f32_16x16x128_f8f6f4, fmt 0
// (e4m3), per-operand e8m0 scales SA/SB (0x7F = 1.0, 0x7B = 2^-4).
// LDS rows are 128 B (8 chunks); chunk-rotation swizzle mod 8 keeps staging
// and the paired ds_read_b128 fragment reads at the LDS bank floor.
// Double-buffered (2x16 KB per operand, caller-provided LDS), counted vmcnt.
template <bool ROWSUM, int SA = 0x7F, int SB = 0x7F>
__device__ __forceinline__ void gemm_bt_mx(const unsigned char* __restrict__ A,
                                           const unsigned char* __restrict__ B,
                                           int K, int lda, int ldb,
                                           f32x4 acc[4][4], f32x4 accl[4],
                                           unsigned char* AsB, unsigned char* BsB) {
  const int tid  = threadIdx.x;
  const int wave = tid >> 6;
  const int lane = tid & 63;
  const int wm = (wave >> 1) * 64;
  const int wn = (wave & 1) * 64;
  // staging: per cp16 call lane covers row (lane>>3), LDS chunk (lane&7);
  // rotation: LDS chunk c of row r holds global chunk (c - r) & 7.
  const int srow = lane >> 3;
  const int gch  = ((lane & 7) - srow) & 7;
  const unsigned char* gA = A + (size_t)(wave * 32 + srow) * lda + gch * 16;
  const unsigned char* gB = B + (size_t)(wave * 32 + srow) * ldb + gch * 16;
  const int lofs = wave * 32 * 128;
  const int fr = lane & 15;
  const int q  = lane >> 4;
  // lane wants global chunks 2q, 2q+1 of its row (32 B = K-128 fragment)
  const int co0 = ((2 * q     + fr) & 7) * 16;
  const int co1 = ((2 * q + 1 + fr) & 7) * 16;
  const i32x8 vones = {0x38383838, 0x38383838, 0x38383838, 0x38383838,
                       0x38383838, 0x38383838, 0x38383838, 0x38383838};

  const int nT = K >> 7;
  // prologue: stage tile 0 into buffer 0
#pragma unroll
  for (int cc = 0; cc < 4; ++cc) {
    cp16(gA + (size_t)(cc * 8) * lda, AsB + lofs + cc * 1024);
    cp16(gB + (size_t)(cc * 8) * ldb, BsB + lofs + cc * 1024);
  }
  gA += 128; gB += 128;

#pragma unroll 1
  for (int t = 0; t < nT; ++t) {
    const int cur = t & 1;
    if (t + 1 < nT) {
      // stage tile t+1 into the other buffer; it flies across this tile's
      // compute and is drained by next iteration's vmcnt(8).
#pragma unroll
      for (int cc = 0; cc < 4; ++cc) {
        cp16(gA + (size_t)(cc * 8) * lda, AsB + (cur ^ 1) * 16384 + lofs + cc * 1024);
        cp16(gB + (size_t)(cc * 8) * ldb, BsB + (cur ^ 1) * 16384 + lofs + cc * 1024);
      }
      gA += 128; gB += 128;
      asm volatile("s_waitcnt vmcnt(8)" ::: "memory");  // tile t resident
    } else {
      asm volatile("s_waitcnt vmcnt(0)" ::: "memory");  // last tile resident
    }
    __builtin_amdgcn_s_barrier();   // tile t visible to all waves

    i32x8 a[4], b[4];
    const unsigned char* Ab = AsB + cur * 16384;
    const unsigned char* Bb = BsB + cur * 16384;
#pragma unroll
    for (int i = 0; i < 4; ++i) {
      const int ro = (wm + i * 16 + fr) * 128;
      i32x4 lo = *(const i32x4*)(Ab + ro + co0);
      i32x4 hi = *(const i32x4*)(Ab + ro + co1);
      a[i] = __builtin_shufflevector(lo, hi, 0, 1, 2, 3, 4, 5, 6, 7);
    }
#pragma unroll
    for (int j = 0; j < 4; ++j) {
      const int ro = (wn + j * 16 + fr) * 128;
      i32x4 lo = *(const i32x4*)(Bb + ro + co0);
      i32x4 hi = *(const i32x4*)(Bb + ro + co1);
      b[j] = __builtin_shufflevector(lo, hi, 0, 1, 2, 3, 4, 5, 6, 7);
    }
    __builtin_amdgcn_s_setprio(1);
#pragma unroll
    for (int i = 0; i < 4; ++i) {
#pragma unroll
      for (int j = 0; j < 4; ++j)
        acc[i][j] = __builtin_amdgcn_mfma_scale_f32_16x16x128_f8f6f4(
            a[i], b[j], acc[i][j], 0, 0, 0, SA, 0, SB);
      if (ROWSUM)
        accl[i] = __builtin_amdgcn_mfma_scale_f32_16x16x128_f8f6f4(
            a[i], vones, accl[i], 0, 0, 0, SA, 0, 0x7F);
    }
    __builtin_amdgcn_s_setprio(0);
    __builtin_amdgcn_s_barrier();   // all reads of buf[cur] done
  }
}

// ---------------- prep: GroupNorm partials + weight casts (merged) ----------

// blocks [0,1024): partial GN stats -> stats[bg][ch][2] (atomic-free; every
// slot written, so no memset needed).
// blocks [1024,2048): wqkv8 = fp8(qkv_w*16) plain; wproj8 = fp8(proj_w*16)
// with sigma-permuted c columns.
__global__ void __launch_bounds__(256) prep_kernel(const float* __restrict__ x,
                                                   float* __restrict__ stats,
                                                   const float* __restrict__ qkv_w,
                                                   const float* __restrict__ proj_w,
                                                   fp8_t* __restrict__ wqkv8,
                                                   fp8_t* __restrict__ wproj8) {
  __shared__ float rs[256], rss[256];
  const int n = blockIdx.x;
  if (n < 1024) {
    const int bg = n >> 3;       // group id 0..127
    const int ch = n & 7;        // hw chunk 0..7
    const float4* base = (const float4*)(x + (size_t)bg * (CPG_ * HW_)) +
                         (size_t)ch * (CPG_ * HW_ / 4 / 8);
    float s = 0.f, ss = 0.f;
    for (int i = threadIdx.x; i < CPG_ * HW_ / 4 / 8; i += 256) {
      float4 v = base[i];
      s  += v.x + v.y + v.z + v.w;
      ss += v.x * v.x + v.y * v.y + v.z * v.z + v.w * v.w;
    }
    rs[threadIdx.x] = s; rss[threadIdx.x] = ss;
    __syncthreads();
    for (int st = 128; st > 0; st >>= 1) {
      if ((int)threadIdx.x < st) {
        rs[threadIdx.x]  += rs[threadIdx.x + st];
        rss[threadIdx.x] += rss[threadIdx.x + st];
      }
      __syncthreads();
    }
    if (threadIdx.x == 0) {
      stats[(bg * 8 + ch) * 2 + 0] = rs[0];
      stats[(bg * 8 + ch) * 2 + 1] = rss[0];
    }
  } else {
    const int idx = (n - 1024) * 256 + threadIdx.x;   // quad index
    const int t = idx * 4;
    const int nq = 1536 * 512;
    if (t < nq) {
      u32 dw = 0;
      dw = (u32)__builtin_amdgcn_cvt_pk_fp8_f32(qkv_w[t] * 16.f, qkv_w[t + 1] * 16.f, (int)dw, false);
      dw = (u32)__builtin_amdgcn_cvt_pk_fp8_f32(qkv_w[t + 2] * 16.f, qkv_w[t + 3] * 16.f, (int)dw, true);
      *(u32*)((unsigned char*)wqkv8 + t) = dw;
    } else {
      const int tt = t - nq;          // o*512 + p, p multiple of 4
      const int o = tt >> 9;
      const int p = tt & 511;
      float v[4];
#pragma unroll
      for (int e = 0; e < 4; ++e) {
        const int pe = p + e;
        const int off = pe & 63;
        const int c = (pe & ~63) + ((off & 3) << 4) + (off >> 2);  // sigma(pe)
        v[e] = proj_w[(o << 9) + c] * 16.f;
      }
      u32 dw = 0;
      dw = (u32)__builtin_amdgcn_cvt_pk_fp8_f32(v[0], v[1], (int)dw, false);
      dw = (u32)__builtin_amdgcn_cvt_pk_fp8_f32(v[2], v[3], (int)dw, true);
      *(u32*)((unsigned char*)wproj8 + tt) = dw;
    }
  }
}

// normalize + transpose: x[b][c][i] (fp32) -> xnT8[b][i][c] (fp8, plain order)
// Reduces the 8 per-chunk stat partials inline (deterministic order).
__global__ void __launch_bounds__(256) norm_tr_kernel(const float* __restrict__ x,
                                                      const float* __restrict__ stats,
                                                      const float* __restrict__ nw,
                                                      const float* __restrict__ nb,
                                                      fp8_t* __restrict__ xnT8) {
  __shared__ float tile[64][65];   // [c_off][i_off]
  const int b  = blockIdx.z;
  const int i0 = blockIdx.x * 64;   // hw
  const int c0 = blockIdx.y * 64;   // channel
  const int tx = threadIdx.x & 63;
  const int ty = threadIdx.x >> 6;  // 0..3
  const int cbase = c0 + ty * 16;
  const int g = cbase >> 4;         // group const across r (16 channels per ty)
  const float inv = 1.f / (float)(CPG_ * HW_);
  float sum = 0.f, ssum = 0.f;
#pragma unroll
  for (int ch = 0; ch < 8; ++ch) {
    sum  += stats[((b * G_ + g) * 8 + ch) * 2 + 0];
    ssum += stats[((b * G_ + g) * 8 + ch) * 2 + 1];
  }
  const float mean = sum * inv;
  const float rstd = rsqrtf(ssum * inv - mean * mean + EPS_);
#pragma unroll
  for (int r = 0; r < 16; ++r) {
    const int c = cbase + r;
    float v = x[((size_t)b * C_ + c) * HW_ + i0 + tx];
    tile[ty * 16 + r][tx] = (v - mean) * rstd * nw[c] + nb[c];
  }
  __syncthreads();
  const int il = threadIdx.x >> 2;
  const int q4 = threadIdx.x & 3;
#pragma unroll
  for (int m = 0; m < 4; ++m) {
    const int cq = q4 + m * 4;     // 0..15
    u32 dw = 0;
    dw = (u32)__builtin_amdgcn_cvt_pk_fp8_f32(tile[cq * 4 + 0][il], tile[cq * 4 + 1][il], (int)dw, false);
    dw = (u32)__builtin_amdgcn_cvt_pk_fp8_f32(tile[cq * 4 + 2][il], tile[cq * 4 + 3][il], (int)dw, true);
    *(u32*)((unsigned char*)xnT8 + ((size_t)b * HW_ + i0 + il) * C_ + c0 + cq * 4) = dw;
  }
}

// ---------------- GEMM kernels ----------------

// Merged qk+v projections (saves a dispatch; v's small grid rides qk's tail).
// blocks [0,1024): QKt8[b][i][sig o] = fp8( xnT8 . wqkv8*2^-4 + bias )
// blocks [1024,1536): V8[b][c][sig j] = fp8( wqkv8_v*2^-4 . xnT8 + bias )
__global__ void __launch_bounds__(256) qkv_gemm_kernel(const fp8_t* __restrict__ xnT8,
                                                       const fp8_t* __restrict__ wqkv8,
                                                       const float* __restrict__ qkv_b,
                                                       fp8_t* __restrict__ QKt8,
                                                       fp8_t* __restrict__ V8) {
  __shared__ __align__(16) unsigned char As[2 * 16384];
  __shared__ __align__(16) unsigned char Bs[2 * 16384];
  const int n = blockIdx.x;
  const int lane = threadIdx.x & 63, wave = threadIdx.x >> 6;
  const int wm = (wave >> 1) * 64, wn = (wave & 1) * 64;
  const int fr = lane & 15, q = lane >> 4;
  f32x4 acc[4][4]; zero_acc(acc);

  if (n < 1024) {
    const int xb = n & 7, yb = (n >> 3) & 31, b = n >> 8;
    const unsigned char* A  = (const unsigned char*)xnT8 + ((size_t)b * HW_ + yb * 128) * C_;
    const unsigned char* Bp = (const unsigned char*)wqkv8 + (size_t)xb * 128 * C_;
    gemm_bt_mx<false, 0x7F, 0x7B>(A, Bp, C_, C_, C_, acc, nullptr, As, Bs);
    const int r0 = yb * 128 + wm + (q << 2);
    const int cb = xb * 128 + wn;       // 64-col group base (true & stored)
    float bias[4];
#pragma unroll
    for (int j = 0; j < 4; ++j) bias[j] = qkv_b[cb + fr + j * 16];  // true cols
#pragma unroll
    for (int i = 0; i < 4; ++i)
#pragma unroll
      for (int r = 0; r < 4; ++r) {
        const int row = r0 + i * 16 + r;
        u32 dw = 0;
        dw = (u32)__builtin_amdgcn_cvt_pk_fp8_f32(acc[i][0][r] + bias[0],
                                                  acc[i][1][r] + bias[1], (int)dw, false);
        dw = (u32)__builtin_amdgcn_cvt_pk_fp8_f32(acc[i][2][r] + bias[2],
                                                  acc[i][3][r] + bias[3], (int)dw, true);
        *(u32*)((unsigned char*)QKt8 + ((size_t)b * HW_ + row) * 1024 + cb + fr * 4) = dw;
      }
  } else {
    const int m = n - 1024;
    const int xb = m & 31, yb = (m >> 5) & 3, b = m >> 7;
    const unsigned char* A  = (const unsigned char*)wqkv8 + (size_t)(1024 + yb * 128) * C_;
    const unsigned char* Bp = (const unsigned char*)xnT8 + ((size_t)b * HW_ + xb * 128) * C_;
    gemm_bt_mx<false, 0x7B, 0x7F>(A, Bp, C_, C_, C_, acc, nullptr, As, Bs);
    const int r0 = yb * 128 + wm + (q << 2);
    const int cb = xb * 128 + wn;       // hw 64-group base
#pragma unroll
    for (int i = 0; i < 4; ++i)
#pragma unroll
      for (int r = 0; r < 4; ++r) {
        const int row = r0 + i * 16 + r;        // c channel (row of V8)
        const float bias = qkv_b[1024 + row];
        u32 dw = 0;
        dw = (u32)__builtin_amdgcn_cvt_pk_fp8_f32(acc[i][0][r] + bias,
                                                  acc[i][1][r] + bias, (int)dw, false);
        dw = (u32)__builtin_amdgcn_cvt_pk_fp8_f32(acc[i][2][r] + bias,
                                                  acc[i][3][r] + bias, (int)dw, true);
        *(u32*)((unsigned char*)V8 + ((size_t)b * C_ + row) * HW_ + cb + fr * 4) = dw;
      }
  }
}

// P8[b][i][sigma-pos j] = fp8( 2^(scale*log2e * q_i.k_j - 4) ); MX-fp8 GEMM.
// XCD-aware 1-D grid: the 32 K-panel blocks sharing a Q row-panel are
// dispatch-adjacent on one XCD (QKt8 panels stay L2-hot per XCD). The whole
// (yb,b) output panel is produced on xcd = (b*32+yb)>>4 — pv exploits this.
__global__ void __launch_bounds__(256) sexp_gemm_kernel(const fp8_t* __restrict__ QKt8,
                                                        fp8_t* __restrict__ P8) {
  __shared__ __align__(16) unsigned char As[2 * 16384];
  __shared__ __align__(16) unsigned char Bs[2 * 16384];
  const int n   = blockIdx.x;            // 4096 blocks
  const int xcd = n & 7;
  const int p   = n >> 3;                // 0..511 within XCD
  const int xb  = p & 31;                // K panel (fastest -> share Q panel)
  const int grp = xcd * 16 + (p >> 5);   // 0..127 = (yb, b) combo
  const int yb  = grp & 31;              // Q panel
  const int b   = grp >> 5;              // batch

  const unsigned char* QKtb = (const unsigned char*)QKt8 + (size_t)b * HW_ * 1024;
  fp8_t* Pb = P8 + (size_t)b * HW_ * HW_;
  f32x4 acc[4][4]; zero_acc(acc);
  const unsigned char* A  = QKtb + (size_t)yb * 128 * 1024;        // Q rows
  const unsigned char* Bp = QKtb + 512 + (size_t)xb * 128 * 1024;  // K rows
  gemm_bt_mx<false>(A, Bp, 512, 1024, 1024, acc, nullptr, As, Bs);
  const int lane = threadIdx.x & 63, wave = threadIdx.x >> 6;
  const int wm = (wave >> 1) * 64, wn = (wave & 1) * 64;
  const int fr = lane & 15, q = lane >> 4;
  const int r0 = yb * 128 + wm + (q << 2);
  const int cb = xb * 128 + wn;          // j 64-group base
#pragma unroll
  for (int i = 0; i < 4; ++i)
#pragma unroll
    for (int r = 0; r < 4; ++r) {
      const int row = r0 + i * 16 + r;
      float e0 = fexp2(fmaf(acc[i][0][r], SEXPC_, -4.0f));
      float e1 = fexp2(fmaf(acc[i][1][r], SEXPC_, -4.0f));
      float e2 = fexp2(fmaf(acc[i][2][r], SEXPC_, -4.0f));
      float e3 = fexp2(fmaf(acc[i][3][r], SEXPC_, -4.0f));
      u32 dw = 0;
      dw = (u32)__builtin_amdgcn_cvt_pk_fp8_f32(e0, e1, (int)dw, false);
      dw = (u32)__builtin_amdgcn_cvt_pk_fp8_f32(e2, e3, (int)dw, true);
      *(u32*)((unsigned char*)Pb + (size_t)row * HW_ + cb + fr * 4) = dw;
    }
}

// hmT8[b][i][sigma-pos c] = fp8( 16 * (sum_j P8 * V8) / rowsum(P8) )
// MX-fp8 GEMM with ones-MFMA row sums. XCD map matches sexp's P-production
// map (same grp->(yb,b) formula => same xcd), with the within-XCD panel
// order REVERSED so pv consumes the last-written (L2-hot) panels first.
__global__ void __launch_bounds__(256) pv_gemm_kernel(const fp8_t* __restrict__ P8,
                                                      const fp8_t* __restrict__ V8,
                                                      fp8_t* __restrict__ hmT8) {
  __shared__ __align__(16) unsigned char As[2 * 16384];
  __shared__ __align__(16) unsigned char Bs[2 * 16384];
  // decode swizzled block id: n = 512 blocks total
  const int n   = blockIdx.x;
  const int xcd = n & 7;           // XCD (round-robin heuristic)
  const int p   = n >> 3;          // 0..63, position within XCD
  const int xb  = p & 3;           // C panel (fastest -> adjacent blocks share P)
  const int gi  = 15 - (p >> 2);   // REVERSED within-XCD group (hottest P first)
  const int grp = xcd * 16 + gi;   // 0..127 = (y,z) group
  const int yb  = grp & 31;        // HW panel
  const int b   = grp >> 5;        // batch

  const unsigned char* A  = (const unsigned char*)P8 + (size_t)b * HW_ * HW_ +
                            (size_t)yb * 128 * HW_;
  const unsigned char* Bp = (const unsigned char*)V8 + (size_t)b * C_ * HW_ +
                            (size_t)xb * 128 * HW_;
  fp8_t* hmTb = hmT8 + (size_t)b * HW_ * C_;

  f32x4 acc[4][4]; zero_acc(acc);
  f32x4 accl[4];
  {
    f32x4 z = {0.f, 0.f, 0.f, 0.f};
#pragma unroll
    for (int i = 0; i < 4; ++i) accl[i] = z;
  }
  gemm_bt_mx<true>(A, Bp, HW_, HW_, HW_, acc, accl, As, Bs);

  const int lane = threadIdx.x & 63, wave = threadIdx.x >> 6;
  const int wm = (wave >> 1) * 64, wn = (wave & 1) * 64;
  const int fr = lane & 15, q = lane >> 4;
  const int r0 = yb * 128 + wm + (q << 2);
  const int cb = xb * 128 + wn;   // c 64-group base (stored sigma-packed)
#pragma unroll
  for (int i = 0; i < 4; ++i)
#pragma unroll
    for (int r = 0; r < 4; ++r) {
      const int row = r0 + i * 16 + r;
      // x16 for fp8 range; undone by 2^-4 in proj. rcp: 1-ulp, fp8-invisible.
      const float rl = 16.f * __builtin_amdgcn_rcpf(accl[i][r]);
      u32 dw = 0;
      dw = (u32)__builtin_amdgcn_cvt_pk_fp8_f32(acc[i][0][r] * rl, acc[i][1][r] * rl, (int)dw, false);
      dw = (u32)__builtin_amdgcn_cvt_pk_fp8_f32(acc[i][2][r] * rl, acc[i][3][r] * rl, (int)dw, true);
      *(u32*)((unsigned char*)hmTb + (size_t)row * C_ + cb + fr * 4) = dw;
    }
}

// out[b][o][i] = x[b][o][i] + proj_b[o] + (wproj8*2^-4)(sigma) . (hmT8*2^-4)(sigma)
__global__ void __launch_bounds__(256) proj_gemm_kernel(const fp8_t* __restrict__ wproj8,
                                                        const fp8_t* __restrict__ hmT8,
                                                        const float* __restrict__ proj_b,
                                                        const float* __restrict__ x,
                                                        float* __restrict__ out) {
  __shared__ __align__(16) unsigned char As[2 * 16384];
  __shared__ __align__(16) unsigned char Bs[2 * 16384];
  const int b = blockIdx.z;
  f32x4 acc[4][4]; zero_acc(acc);
  const unsigned char* A  = (const unsigned char*)wproj8 + (size_t)blockIdx.y * 128 * C_;
  const unsigned char* Bp = (const unsigned char*)hmT8 + ((size_t)b * HW_ + blockIdx.x * 128) * C_;
  gemm_bt_mx<false, 0x7B, 0x7B>(A, Bp, C_, C_, C_, acc, nullptr, As, Bs);
  const int lane = threadIdx.x & 63, wave = threadIdx.x >> 6;
  const int wm = (wave >> 1) * 64, wn = (wave & 1) * 64;
  const int r0 = blockIdx.y * 128 + wm + ((lane >> 4) << 2);
  const int c0 = blockIdx.x * 128 + wn + (lane & 15);
#pragma unroll
  for (int i = 0; i < 4; ++i)
#pragma unroll
    for (int r = 0; r < 4; ++r) {
      const int row = r0 + i * 16 + r;
      const float bias = proj_b[row];
#pragma unroll
      for (int j = 0; j < 4; ++j) {
        const int col = c0 + j * 16;
        const size_t idx = ((size_t)b * C_ + row) * HW_ + col;
        out[idx] = x[idx] + bias + acc[i][j][r];
      }
    }
}

// ---------------- launch ----------------
// Workspace layout (bytes), total ~110 MB:
//   wqkv8  fp8 [1536][512] (x16)         786,432
//   wproj8 fp8 [512][512] (x16, sigma)   262,144
//   stats  f32 [128][8][2]                 8,192
//   xnT8   fp8 [4][4096][512]          8,388,608
//   QKt8   fp8 [4][4096][1024](sig)   16,777,216
//   V8     fp8 [4][512][4096] (sig)    8,388,608
//   hmT8   fp8 [4][4096][512] (x16,sig) 8,388,608
//   P8     fp8 [4][4096][4096](sig)   67,108,864
extern "C" void kernel_launch(void* const* d_in, const int* in_sizes, int n_in,
                              void* d_out, int out_size, void* d_ws, size_t ws_size,
                              hipStream_t stream) {
  const float* x      = (const float*)d_in[0];
  const float* norm_w = (const float*)d_in[1];
  const float* norm_b = (const float*)d_in[2];
  const float* qkv_w  = (const float*)d_in[3];
  const float* qkv_b  = (const float*)d_in[4];
  const float* proj_w = (const float*)d_in[5];
  const float* proj_b = (const float*)d_in[6];
  float* out = (float*)d_out;

  char* ws = (char*)d_ws;
  size_t o = 0;
  fp8_t* wqkv8  = (fp8_t*)(ws + o); o += (size_t)1536 * 512;
  fp8_t* wproj8 = (fp8_t*)(ws + o); o += (size_t)512 * 512;
  float* stats  = (float*)(ws + o); o += 128 * 8 * 2 * 4;
  fp8_t* xnT8   = (fp8_t*)(ws + o); o += (size_t)B_ * HW_ * C_;
  fp8_t* QKt8   = (fp8_t*)(ws + o); o += (size_t)B_ * HW_ * 1024;
  fp8_t* V8     = (fp8_t*)(ws + o); o += (size_t)B_ * C_ * HW_;
  fp8_t* hmT8   = (fp8_t*)(ws + o); o += (size_t)B_ * HW_ * C_;
  fp8_t* P8     = (fp8_t*)(ws + o); o += (size_t)B_ * HW_ * HW_;

  prep_kernel<<<2048, 256, 0, stream>>>(x, stats, qkv_w, proj_w, wqkv8, wproj8);
  norm_tr_kernel<<<dim3(HW_ / 64, C_ / 64, B_), 256, 0, stream>>>(x, stats, norm_w, norm_b, xnT8);
  qkv_gemm_kernel<<<1536, 256, 0, stream>>>(xnT8, wqkv8, qkv_b, QKt8, V8);
  sexp_gemm_kernel<<<4096, 256, 0, stream>>>(QKt8, P8);
  pv_gemm_kernel<<<512, 256, 0, stream>>>(P8, V8, hmT8);
  proj_gemm_kernel<<<dim3(HW_ / 128, C_ / 128, B_), 256, 0, stream>>>(
      wproj8, hmT8, proj_b, x, out);
}